// Round 11
// baseline (728.894 us; speedup 1.0000x reference)
//
#include <hip/hip_runtime.h>
#include <math.h>

#define E_    8
#define D_    1024
#define F_    4096
#define T_    8192
#define CAP_  2560
#define SP_   (T_ * 2)
#define EG_   4

typedef __attribute__((ext_vector_type(4))) float f32x4;
typedef __attribute__((ext_vector_type(8))) short bf16x8;

__device__ __forceinline__ float b2f(unsigned short u) {
    union { unsigned int i; float f; } v; v.i = ((unsigned int)u) << 16; return v.f;
}
__device__ __forceinline__ unsigned short f2b(float f) {
    unsigned int u = __float_as_uint(f);
    unsigned int r = (u + 0x7fff + ((u >> 16) & 1)) >> 16;
    return (unsigned short)r;
}
__device__ __forceinline__ void async16(void* lds, const void* g) {
    __builtin_amdgcn_global_load_lds(
        (const __attribute__((address_space(1))) unsigned int*)g,
        (__attribute__((address_space(3))) unsigned int*)lds, 16, 0, 0);
}

// Stage one 64-row x 64-col bf16 chunk (8KB): linear LDS dest, inverse-swizzled
// global source (rule #21).  goff hoisted by caller.
__device__ __forceinline__ void stage64o(unsigned short* ldsb, const unsigned short* g,
                                         size_t goff, int tid) {
    async16(ldsb + tid * 8, g + goff);
}

// ---------------- router: fp64 logits, top-2, softmax ----------------
__global__ void router_kernel(const float* __restrict__ x, const float* __restrict__ Wr,
                              int* __restrict__ top_i, float* __restrict__ top_w) {
    int wid = threadIdx.x >> 6, lane = threadIdx.x & 63;
    int t = blockIdx.x * 4 + wid;
    double s[E_];
    #pragma unroll
    for (int e = 0; e < E_; e++) s[e] = 0.0;
    const float* xr = x + (size_t)t * D_;
    for (int j = 0; j < D_ / 64; j++) {
        int d = lane + 64 * j;
        double xv = (double)xr[d];
        const float* wr = Wr + d * E_;
        #pragma unroll
        for (int e = 0; e < E_; e++) s[e] += xv * (double)wr[e];
    }
    #pragma unroll
    for (int off = 32; off >= 1; off >>= 1) {
        #pragma unroll
        for (int e = 0; e < E_; e++) s[e] += __shfl_xor(s[e], off, 64);
    }
    if (lane == 0) {
        double best = -1e300, sec = -1e300; int bi = 0, si = 0;
        #pragma unroll
        for (int e = 0; e < E_; e++) {
            double v = s[e];
            v = v > 1e4 ? 1e4 : (v < -1e4 ? -1e4 : v);
            if (v > best) { sec = best; si = bi; best = v; bi = e; }
            else if (v > sec) { sec = v; si = e; }
        }
        double e1 = exp(sec - best);
        double denom = 1.0 + e1 + 1e-12;
        top_i[t * 2 + 0] = bi;  top_i[t * 2 + 1] = si;
        top_w[t * 2 + 0] = (float)(1.0 / denom);
        top_w[t * 2 + 1] = (float)(e1 / denom);
    }
}

// -------- stable per-expert position scan + capacity prune (1 block) --------
#define SCAN_T 256
#define CHUNK  (SP_ / SCAN_T)
__global__ void scan_kernel(const int* __restrict__ top_i,
                            int* __restrict__ slot, int* __restrict__ list,
                            int* __restrict__ count) {
    __shared__ int lc[SCAN_T][E_];
    int tid = threadIdx.x;
    int cnt[E_];
    #pragma unroll
    for (int e = 0; e < E_; e++) cnt[e] = 0;
    int base = tid * CHUNK;
    for (int i = 0; i < CHUNK; i++) cnt[top_i[base + i]]++;
    #pragma unroll
    for (int e = 0; e < E_; e++) lc[tid][e] = cnt[e];
    __syncthreads();
    if (tid < E_) {
        int run = 0;
        for (int i = 0; i < SCAN_T; i++) { int c = lc[i][tid]; lc[i][tid] = run; run += c; }
        count[tid] = run;
    }
    __syncthreads();
    int off[E_];
    #pragma unroll
    for (int e = 0; e < E_; e++) off[e] = lc[tid][e];
    for (int i = 0; i < CHUNK; i++) {
        int s = base + i;
        int e = top_i[s];
        int p = off[e]++;
        if (p < CAP_) { slot[s] = e * CAP_ + p; list[e * CAP_ + p] = s; }
        else slot[s] = -1;
    }
}

// ---------------- dispatch: pack x rows into xe (bf16), zero pads ----------------
__global__ void dispatch_kernel(const float* __restrict__ x, const int* __restrict__ list,
                                const int* __restrict__ count, unsigned short* __restrict__ xe) {
    int c = blockIdx.x, e = blockIdx.y, tid = threadIdx.x;
    unsigned short* dst = xe + ((size_t)e * CAP_ + c) * D_;
    ushort4 o;
    if (c < count[e]) {
        int t = list[e * CAP_ + c] >> 1;
        float4 v = ((const float4*)(x + (size_t)t * D_))[tid];
        o.x = f2b(v.x); o.y = f2b(v.y); o.z = f2b(v.z); o.w = f2b(v.w);
    } else { o.x = 0; o.y = 0; o.z = 0; o.w = 0; }
    ((ushort4*)dst)[tid] = o;
}

// -------- transpose + fp32->bf16: src[e][r][c] -> dst[e][c][r], 64x64 tiles --------
__global__ void transpose_conv64(const float* __restrict__ src, unsigned short* __restrict__ dst,
                                 int R, int C, size_t srcE, size_t dstE) {
    __shared__ float tile[64][69];
    int e = blockIdx.z;
    const float* s = src + (size_t)e * srcE;
    unsigned short* d = dst + (size_t)e * dstE;
    int tx = threadIdx.x, ty = threadIdx.y;
    int c0 = blockIdx.x * 64, r0 = blockIdx.y * 64;
    #pragma unroll
    for (int i = 0; i < 4; i++) {
        int row = ty + i * 16;
        float4 v = *(const float4*)(s + (size_t)(r0 + row) * C + c0 + 4 * tx);
        tile[row][4 * tx + 0] = v.x; tile[row][4 * tx + 1] = v.y;
        tile[row][4 * tx + 2] = v.z; tile[row][4 * tx + 3] = v.w;
    }
    __syncthreads();
    #pragma unroll
    for (int i = 0; i < 4; i++) {
        int c = ty + i * 16;
        ushort4 o;
        o.x = f2b(tile[4 * tx + 0][c]);
        o.y = f2b(tile[4 * tx + 1][c]);
        o.z = f2b(tile[4 * tx + 2][c]);
        o.w = f2b(tile[4 * tx + 3][c]);
        *(ushort4*)(d + (size_t)(c0 + c) * R + r0 + 4 * tx) = o;
    }
}

// ============================================================================
// gemm1_320 (gemm2_8p geometry, dual-B): H[e] = silu(xe@W1) * (xe@W3).
// BM=320, BN=128 per matrix (256 effective), BK=64, 8 waves (2M x 4N),
// wave out 160x32 per matrix.  20 MFMA/phase (5m x 2n x 2mats x 1kk),
// max 9 reads/phase.  LDS 144KB: A 2x40KB, B1 2x16KB, B3 2x16KB.
// 8 phases / 2 K-tiles (mirrors gemm2_8p's audited vmcnt(4)@P4/P8 timeline):
//   P1 (mh0,kk0) load b*f0<-Bbuf; stage Abuf1<-t+1 [3u]
//   P2 (mh1,kk0) load b*f1<-Bbuf; stage Abuf1 [2u]
//   P3 (mh0,kk1);                 stage B1buf0<-t+2 [2u]
//   P4 (mh1,kk1);                 stage B3buf0<-t+2 [2u]; vmcnt(4)
//   P5-P8 mirror on buf1 (Abuf0<-t+2, B*buf1<-t+3); vmcnt(4) at P8.
// Grid (8,32,EG)=1024 blocks, bijective XCD swizzle.
// ============================================================================
#define G1N_PHASE(ABUF, MH, KK, LB0, LB1, BBUF, STAGE, VMC)                    \
  {                                                                            \
    bf16x8 af[5];                                                              \
    _Pragma("unroll")                                                          \
    for (int mi = 0; mi < 5; mi++)                                             \
      af[mi] = *(const bf16x8*)(g1a##KK + (ABUF) * 40960 + ((MH) * 5 + mi) * 2048); \
    if (LB0) {                                                                 \
      _Pragma("unroll")                                                        \
      for (int n = 0; n < 2; n++) {                                            \
        b1f0[n] = *(const bf16x8*)(b1k0 + (BBUF) * 16384 + n * 2048);          \
        b3f0[n] = *(const bf16x8*)(b3k0 + (BBUF) * 16384 + n * 2048);          \
      }                                                                        \
    }                                                                          \
    if (LB1) {                                                                 \
      _Pragma("unroll")                                                        \
      for (int n = 0; n < 2; n++) {                                            \
        b1f1[n] = *(const bf16x8*)(b1k1 + (BBUF) * 16384 + n * 2048);          \
        b3f1[n] = *(const bf16x8*)(b3k1 + (BBUF) * 16384 + n * 2048);          \
      }                                                                        \
    }                                                                          \
    STAGE;                                                                     \
    __builtin_amdgcn_s_barrier();                                              \
    asm volatile("s_waitcnt lgkmcnt(0)" ::: "memory");                         \
    __builtin_amdgcn_sched_barrier(0);                                         \
    __builtin_amdgcn_s_setprio(1);                                             \
    _Pragma("unroll")                                                          \
    for (int mi = 0; mi < 5; mi++)                                             \
      _Pragma("unroll")                                                        \
      for (int n = 0; n < 2; n++) {                                            \
        acc1[(MH) * 5 + mi][n] = __builtin_amdgcn_mfma_f32_16x16x32_bf16(      \
            af[mi], b1f##KK[n], acc1[(MH) * 5 + mi][n], 0, 0, 0);              \
        acc3[(MH) * 5 + mi][n] = __builtin_amdgcn_mfma_f32_16x16x32_bf16(      \
            af[mi], b3f##KK[n], acc3[(MH) * 5 + mi][n], 0, 0, 0);              \
      }                                                                        \
    __builtin_amdgcn_s_setprio(0);                                             \
    if (VMC) asm volatile("s_waitcnt vmcnt(4)" ::: "memory");                  \
    __builtin_amdgcn_s_barrier();                                              \
  }

__global__ __launch_bounds__(512, 2) void gemm1_320(
    const unsigned short* __restrict__ xe,    // [EG][CAP][D]
    const unsigned short* __restrict__ WT13,  // [EG][2F][D]
    unsigned short* __restrict__ H) {         // [EG][CAP][F]
    __shared__ unsigned short As[2 * 20480];      // 80KB (320x64 per buf)
    __shared__ unsigned short B1s[2 * 8192];      // 32KB (128x64 per buf)
    __shared__ unsigned short B3s[2 * 8192];      // 32KB
    const int tid = threadIdx.x;
    const int lane = tid & 63, wid = tid >> 6;
    const int wr = wid >> 2, wc = wid & 3;
    const int lrow = lane & 15, lhi = lane >> 4;
    // bijective XCD swizzle: grid (8,32,EG) = 1024 blocks, 1024%8==0.
    const int fid = blockIdx.x + 8 * (blockIdx.y + 32 * blockIdx.z);
    const int swz = (fid & 7) * 128 + (fid >> 3);
    const int bm = swz & 7;
    const int bn = (swz >> 3) & 31;
    const int e  = swz >> 8;
    const int m0 = bm * 320, n0 = bn * 128;
    const unsigned short* A  = xe + (size_t)e * CAP_ * D_ + (size_t)m0 * D_;
    const unsigned short* B1 = WT13 + (size_t)e * 2 * F_ * D_ + (size_t)n0 * D_;
    const unsigned short* B3 = B1 + (size_t)F_ * D_;
    unsigned short* Hout = H + (size_t)e * CAP_ * F_;

    const int xsw = lrow & 7;
    const char* g1a0 = (const char*)As  + wr * 20480 + lrow * 128 + ((lhi    ) ^ xsw) * 16;
    const char* g1a1 = (const char*)As  + wr * 20480 + lrow * 128 + ((4 + lhi) ^ xsw) * 16;
    const char* b1k0 = (const char*)B1s + wc * 4096  + lrow * 128 + ((lhi    ) ^ xsw) * 16;
    const char* b1k1 = (const char*)B1s + wc * 4096  + lrow * 128 + ((4 + lhi) ^ xsw) * 16;
    const char* b3k0 = (const char*)B3s + wc * 4096  + lrow * 128 + ((lhi    ) ^ xsw) * 16;
    const char* b3k1 = (const char*)B3s + wc * 4096  + lrow * 128 + ((4 + lhi) ^ xsw) * 16;
    const size_t goff = (size_t)(tid >> 3) * D_ + (size_t)(((tid & 7) ^ ((tid >> 3) & 7)) * 8);

    f32x4 acc1[10][2], acc3[10][2];
    #pragma unroll
    for (int m = 0; m < 10; m++)
        #pragma unroll
        for (int n = 0; n < 2; n++) {
            f32x4 z = {0.f, 0.f, 0.f, 0.f};
            acc1[m][n] = z; acc3[m][n] = z;
        }
    bf16x8 b1f0[2], b1f1[2], b3f0[2], b3f1[2];

    // prologue: buf0 <- tile0 (A 5u, B1 2u, B3 2u); buf1.B <- tile1 (4u)
    stage64o(As,          A,                        goff, tid);
    stage64o(As + 4096,   A + (size_t)64  * D_,     goff, tid);
    stage64o(As + 8192,   A + (size_t)128 * D_,     goff, tid);
    stage64o(As + 12288,  A + (size_t)192 * D_,     goff, tid);
    stage64o(As + 16384,  A + (size_t)256 * D_,     goff, tid);
    stage64o(B1s,         B1,                       goff, tid);
    stage64o(B1s + 4096,  B1 + (size_t)64 * D_,     goff, tid);
    stage64o(B3s,         B3,                       goff, tid);
    stage64o(B3s + 4096,  B3 + (size_t)64 * D_,     goff, tid);
    stage64o(B1s + 8192,         B1 + 64,                    goff, tid);
    stage64o(B1s + 8192 + 4096,  B1 + (size_t)64 * D_ + 64,  goff, tid);
    stage64o(B3s + 8192,         B3 + 64,                    goff, tid);
    stage64o(B3s + 8192 + 4096,  B3 + (size_t)64 * D_ + 64,  goff, tid);
    asm volatile("s_waitcnt vmcnt(4)" ::: "memory");   // buf0 landed; buf1.B in flight
    __builtin_amdgcn_s_barrier();

    for (int it = 0; it < 8; ++it) {                  // NT=16, 2 K-tiles/iter
        const int t = 2 * it;
        const int k1 = (t + 1) * 64;
        const int k2 = (t + 2 < 16 ? t + 2 : 15) * 64;
        const int k3 = (t + 3 < 16 ? t + 3 : 15) * 64;
        G1N_PHASE(0, 0, 0, 1, 0, 0,
            { stage64o(As + 20480,         A + k1, goff, tid);
              stage64o(As + 20480 + 4096,  A + (size_t)64  * D_ + k1, goff, tid);
              stage64o(As + 20480 + 8192,  A + (size_t)128 * D_ + k1, goff, tid); }, 0)
        G1N_PHASE(0, 1, 0, 0, 1, 0,
            { stage64o(As + 20480 + 12288, A + (size_t)192 * D_ + k1, goff, tid);
              stage64o(As + 20480 + 16384, A + (size_t)256 * D_ + k1, goff, tid); }, 0)
        G1N_PHASE(0, 0, 1, 0, 0, 0,
            { stage64o(B1s,        B1 + k2, goff, tid);
              stage64o(B1s + 4096, B1 + (size_t)64 * D_ + k2, goff, tid); }, 0)
        G1N_PHASE(0, 1, 1, 0, 0, 0,
            { stage64o(B3s,        B3 + k2, goff, tid);
              stage64o(B3s + 4096, B3 + (size_t)64 * D_ + k2, goff, tid); }, 1)
        G1N_PHASE(1, 0, 0, 1, 0, 1,
            { stage64o(As,         A + k2, goff, tid);
              stage64o(As + 4096,  A + (size_t)64  * D_ + k2, goff, tid);
              stage64o(As + 8192,  A + (size_t)128 * D_ + k2, goff, tid); }, 0)
        G1N_PHASE(1, 1, 0, 0, 1, 1,
            { stage64o(As + 12288, A + (size_t)192 * D_ + k2, goff, tid);
              stage64o(As + 16384, A + (size_t)256 * D_ + k2, goff, tid); }, 0)
        G1N_PHASE(1, 0, 1, 0, 0, 1,
            { stage64o(B1s + 8192,        B1 + k3, goff, tid);
              stage64o(B1s + 8192 + 4096, B1 + (size_t)64 * D_ + k3, goff, tid); }, 0)
        G1N_PHASE(1, 1, 1, 0, 0, 1,
            { stage64o(B3s + 8192,        B3 + k3, goff, tid);
              stage64o(B3s + 8192 + 4096, B3 + (size_t)64 * D_ + k3, goff, tid); }, 1)
    }

    const int crow = m0 + wr * 160 + lhi * 4;
    const int ccol = n0 + wc * 32 + lrow;
    #pragma unroll
    for (int m = 0; m < 10; m++)
        #pragma unroll
        for (int n = 0; n < 2; n++)
            #pragma unroll
            for (int r = 0; r < 4; r++) {
                float g1 = acc1[m][n][r], g3 = acc3[m][n][r];
                float h = g1 / (1.f + expf(-g1)) * g3;
                Hout[(size_t)(crow + m * 16 + r) * F_ + ccol + n * 16] = f2b(h);
            }
}

// ============================================================================
// gemm2_8p (round-10 proven): Ye[e] = H[e] @ WT2[e]^T for ALL 8 experts.
// ============================================================================
#define G2N_PHASE(ABUF, MH, KK, LB0, LB1, BBUF, STAGE, VMC)                    \
  {                                                                            \
    bf16x8 af[5];                                                              \
    _Pragma("unroll")                                                          \
    for (int mi = 0; mi < 5; mi++)                                             \
      af[mi] = *(const bf16x8*)(g2a##KK + (ABUF) * 40960 + ((MH) * 5 + mi) * 2048); \
    if (LB0) {                                                                 \
      _Pragma("unroll")                                                        \
      for (int n = 0; n < 4; n++)                                              \
        bfr0[n] = *(const bf16x8*)(g2b0_ + (BBUF) * 32768 + n * 2048);         \
    }                                                                          \
    if (LB1) {                                                                 \
      _Pragma("unroll")                                                        \
      for (int n = 0; n < 4; n++)                                              \
        bfr1[n] = *(const bf16x8*)(g2b1_ + (BBUF) * 32768 + n * 2048);         \
    }                                                                          \
    STAGE;                                                                     \
    __builtin_amdgcn_s_barrier();                                              \
    asm volatile("s_waitcnt lgkmcnt(0)" ::: "memory");                         \
    __builtin_amdgcn_sched_barrier(0);                                         \
    __builtin_amdgcn_s_setprio(1);                                             \
    _Pragma("unroll")                                                          \
    for (int mi = 0; mi < 5; mi++)                                             \
      _Pragma("unroll")                                                        \
      for (int n = 0; n < 4; n++)                                              \
        acc[(MH) * 5 + mi][n] = __builtin_amdgcn_mfma_f32_16x16x32_bf16(       \
            af[mi], bfr##KK[n], acc[(MH) * 5 + mi][n], 0, 0, 0);               \
    __builtin_amdgcn_s_setprio(0);                                             \
    if (VMC) asm volatile("s_waitcnt vmcnt(4)" ::: "memory");                  \
    __builtin_amdgcn_s_barrier();                                              \
  }

__global__ __launch_bounds__(512, 2) void gemm2_8p(
    const unsigned short* __restrict__ Hb,   // [8][CAP][F]
    const unsigned short* __restrict__ WT2,  // [8][D][F]
    unsigned short* __restrict__ Ye) {       // [8][CAP][D]
    __shared__ unsigned short As[2 * 20480];      // 80KB (320x64 per buf)
    __shared__ unsigned short Bs[2 * 16384];      // 64KB (256x64 per buf)
    const int tid = threadIdx.x;
    const int lane = tid & 63, wid = tid >> 6;
    const int wr = wid >> 2, wc = wid & 3;
    const int lrow = lane & 15, lhi = lane >> 4;
    const int fid = blockIdx.x + 8 * (blockIdx.y + 4 * blockIdx.z);
    const int swz = (fid & 7) * 32 + (fid >> 3);
    const int bm = swz & 7;
    const int bn = (swz >> 3) & 3;
    const int e  = swz >> 5;
    const int m0 = bm * 320, n0 = bn * 256;
    const unsigned short* A = Hb + (size_t)e * CAP_ * F_ + (size_t)m0 * F_;
    const unsigned short* B = WT2 + (size_t)e * D_ * F_ + (size_t)n0 * F_;
    unsigned short* C = Ye + (size_t)e * CAP_ * D_;

    const int xsw = lrow & 7;
    const char* g2a0  = (const char*)As + wr * 20480 + lrow * 128 + ((lhi    ) ^ xsw) * 16;
    const char* g2a1  = (const char*)As + wr * 20480 + lrow * 128 + ((4 + lhi) ^ xsw) * 16;
    const char* g2b0_ = (const char*)Bs + wc * 8192  + lrow * 128 + ((lhi    ) ^ xsw) * 16;
    const char* g2b1_ = (const char*)Bs + wc * 8192  + lrow * 128 + ((4 + lhi) ^ xsw) * 16;
    const size_t goff = (size_t)(tid >> 3) * F_ + (size_t)(((tid & 7) ^ ((tid >> 3) & 7)) * 8);

    f32x4 acc[10][4];
    #pragma unroll
    for (int m = 0; m < 10; m++)
        #pragma unroll
        for (int n = 0; n < 4; n++) { f32x4 z = {0.f, 0.f, 0.f, 0.f}; acc[m][n] = z; }
    bf16x8 bfr0[4], bfr1[4];

    #define STA0(BUF, SRC)                                                      \
        { stage64o(As + (BUF) * 20480,        (SRC), goff, tid);                \
          stage64o(As + (BUF) * 20480 + 4096, (SRC) + (size_t)64  * F_, goff, tid); \
          stage64o(As + (BUF) * 20480 + 8192, (SRC) + (size_t)128 * F_, goff, tid); }
    #define STA1(BUF, SRC)                                                      \
        { stage64o(As + (BUF) * 20480 + 12288, (SRC) + (size_t)192 * F_, goff, tid); \
          stage64o(As + (BUF) * 20480 + 16384, (SRC) + (size_t)256 * F_, goff, tid); }
    #define STB0(BUF, SRC)                                                      \
        { stage64o(Bs + (BUF) * 16384,        (SRC), goff, tid);                \
          stage64o(Bs + (BUF) * 16384 + 4096, (SRC) + (size_t)64 * F_, goff, tid); }
    #define STB1(BUF, SRC)                                                      \
        { stage64o(Bs + (BUF) * 16384 + 8192,  (SRC) + (size_t)128 * F_, goff, tid); \
          stage64o(Bs + (BUF) * 16384 + 12288, (SRC) + (size_t)192 * F_, goff, tid); }

    STA0(0, A) STA1(0, A)
    STB0(0, B) STB1(0, B)
    STB0(1, B + 64) STB1(1, B + 64)
    asm volatile("s_waitcnt vmcnt(4)" ::: "memory");
    __builtin_amdgcn_s_barrier();

    for (int it = 0; it < 32; ++it) {                 // NT=64, 2 K-tiles/iter
        const int t = 2 * it;
        const int k1 = (t + 1) * 64;
        const int k2 = (t + 2 < 64 ? t + 2 : 63) * 64;
        const int k3 = (t + 3 < 64 ? t + 3 : 63) * 64;
        G2N_PHASE(0, 0, 0, 1, 0, 0, STA0(1, A + k1), 0)
        G2N_PHASE(0, 1, 0, 0, 1, 0, STA1(1, A + k1), 0)
        G2N_PHASE(0, 0, 1, 0, 0, 0, STB0(0, B + k2), 0)
        G2N_PHASE(0, 1, 1, 0, 0, 0, STB1(0, B + k2), 1)
        G2N_PHASE(1, 0, 0, 1, 0, 1, STA0(0, A + k2), 0)
        G2N_PHASE(1, 1, 0, 0, 1, 1, STA1(0, A + k2), 0)
        G2N_PHASE(1, 0, 1, 0, 0, 1, STB0(1, B + k3), 0)
        G2N_PHASE(1, 1, 1, 0, 0, 1, STB1(1, B + k3), 1)
    }
    #undef STA0
    #undef STA1
    #undef STB0
    #undef STB1

    const int crow = m0 + wr * 160 + lhi * 4;
    const int ccol = n0 + wc * 64 + lrow;
    #pragma unroll
    for (int m = 0; m < 10; m++)
        #pragma unroll
        for (int n = 0; n < 4; n++)
            #pragma unroll
            for (int r = 0; r < 4; r++)
                C[(size_t)(crow + m * 16 + r) * D_ + ccol + n * 16] = f2b(acc[m][n][r]);
}

// ============================================================================
// gemm2_4p (fallback when ws too small for 8-expert Hg)
// ============================================================================
#define G2_PHASE(ABUF, MH, LOADB, BBUF, STAGE, VMC)                            \
  {                                                                            \
    bf16x8 af[5][2];                                                           \
    _Pragma("unroll")                                                          \
    for (int mi = 0; mi < 5; mi++) {                                           \
      af[mi][0] = *(const bf16x8*)(f2a0 + (ABUF) * 40960 + ((MH) * 5 + mi) * 2048); \
      af[mi][1] = *(const bf16x8*)(f2a1 + (ABUF) * 40960 + ((MH) * 5 + mi) * 2048); \
    }                                                                          \
    if (LOADB) {                                                               \
      _Pragma("unroll")                                                        \
      for (int n = 0; n < 2; n++) {                                            \
        bf[n][0] = *(const bf16x8*)(f2b0 + (BBUF) * 16384 + n * 2048);         \
        bf[n][1] = *(const bf16x8*)(f2b1 + (BBUF) * 16384 + n * 2048);         \
      }                                                                        \
    }                                                                          \
    STAGE;                                                                     \
    __builtin_amdgcn_s_barrier();                                              \
    asm volatile("s_waitcnt lgkmcnt(0)" ::: "memory");                         \
    __builtin_amdgcn_sched_barrier(0);                                         \
    __builtin_amdgcn_s_setprio(1);                                             \
    _Pragma("unroll")                                                          \
    for (int mi = 0; mi < 5; mi++)                                             \
      _Pragma("unroll")                                                        \
      for (int n = 0; n < 2; n++)                                              \
        _Pragma("unroll")                                                      \
        for (int kk = 0; kk < 2; kk++)                                         \
          acc[(MH) * 5 + mi][n] = __builtin_amdgcn_mfma_f32_16x16x32_bf16(     \
              af[mi][kk], bf[n][kk], acc[(MH) * 5 + mi][n], 0, 0, 0);          \
    __builtin_amdgcn_s_setprio(0);                                             \
    if (VMC) asm volatile("s_waitcnt vmcnt(2)" ::: "memory");                  \
    __builtin_amdgcn_s_barrier();                                              \
  }

__global__ __launch_bounds__(512, 2) void gemm2_4p(
    const unsigned short* __restrict__ Hb,
    const unsigned short* __restrict__ WT2,
    unsigned short* __restrict__ Ye) {
    __shared__ unsigned short As[2 * 20480];
    __shared__ unsigned short Bs[2 * 8192];
    const int tid = threadIdx.x;
    const int lane = tid & 63, wid = tid >> 6;
    const int wr = wid >> 2, wc = wid & 3;
    const int lrow = lane & 15, lhi = lane >> 4;
    const int fid = blockIdx.x + 8 * (blockIdx.y + 8 * blockIdx.z);
    const int swz = (fid & 7) * 32 + (fid >> 3);
    const int bm = swz & 7;
    const int bn = (swz >> 3) & 7;
    const int e  = swz >> 6;
    const int m0 = bm * 320, n0 = bn * 128;
    const unsigned short* A = Hb + (size_t)e * CAP_ * F_ + (size_t)m0 * F_;
    const unsigned short* B = WT2 + (size_t)e * D_ * F_ + (size_t)n0 * F_;
    unsigned short* C = Ye + (size_t)e * CAP_ * D_;

    const int xsw = lrow & 7;
    const char* f2a0 = (const char*)As + wr * 20480 + lrow * 128 + ((lhi    ) ^ xsw) * 16;
    const char* f2a1 = (const char*)As + wr * 20480 + lrow * 128 + ((4 + lhi) ^ xsw) * 16;
    const char* f2b0 = (const char*)Bs + wc * 4096  + lrow * 128 + ((lhi    ) ^ xsw) * 16;
    const char* f2b1 = (const char*)Bs + wc * 4096  + lrow * 128 + ((4 + lhi) ^ xsw) * 16;
    const size_t goff = (size_t)(tid >> 3) * F_ + (size_t)(((tid & 7) ^ ((tid >> 3) & 7)) * 8);

    f32x4 acc[10][2];
    #pragma unroll
    for (int m = 0; m < 10; m++)
        #pragma unroll
        for (int n = 0; n < 2; n++) { f32x4 z = {0.f, 0.f, 0.f, 0.f}; acc[m][n] = z; }
    bf16x8 bf[2][2];

    #define STAGE_A(BUF, KOFF)                                                  \
        { _Pragma("unroll")                                                     \
          for (int j = 0; j < 5; j++)                                           \
            stage64o(As + (BUF) * 20480 + j * 4096,                             \
                     A + (size_t)(j * 64) * F_ + (KOFF), goff, tid); }
    #define STAGE_B(BUF, KOFF)                                                  \
        { stage64o(Bs + (BUF) * 8192,        B + (KOFF), goff, tid);            \
          stage64o(Bs + (BUF) * 8192 + 4096, B + (size_t)64 * F_ + (KOFF), goff, tid); }

    STAGE_A(0, 0)
    STAGE_B(0, 0)
    STAGE_B(1, 64)
    asm volatile("s_waitcnt vmcnt(2)" ::: "memory");
    __builtin_amdgcn_s_barrier();

    for (int it = 0; it < 32; ++it) {
        const int t = 2 * it;
        const int k1 = (t + 1) * 64;
        const int k2 = (t + 2 < 64 ? t + 2 : 63) * 64;
        const int k3 = (t + 3 < 64 ? t + 3 : 63) * 64;
        G2_PHASE(0, 0, 1, 0, STAGE_A(1, k1), 0)
        G2_PHASE(0, 1, 0, 0, STAGE_B(0, k2), 1)
        G2_PHASE(1, 0, 1, 1, STAGE_A(0, k2), 0)
        G2_PHASE(1, 1, 0, 1, STAGE_B(1, k3), 1)
    }
    #undef STAGE_A
    #undef STAGE_B

    const int crow = m0 + wr * 160 + lhi * 4;
    const int ccol = n0 + wc * 32 + lrow;
    #pragma unroll
    for (int m = 0; m < 10; m++)
        #pragma unroll
        for (int n = 0; n < 2; n++)
            #pragma unroll
            for (int r = 0; r < 4; r++)
                C[(size_t)(crow + m * 16 + r) * D_ + ccol + n * 16] = f2b(acc[m][n][r]);
}

// ---------------- combine: out[t] = sum_k w[t,k] * Ye[slot(t,k)] ----------------
__global__ void combine_kernel(const unsigned short* __restrict__ Ye, const int* __restrict__ slot,
                               const float* __restrict__ w, float* __restrict__ out) {
    int t = blockIdx.x, tid = threadIdx.x;
    float4 r = {0.f, 0.f, 0.f, 0.f};
    #pragma unroll
    for (int k = 0; k < 2; k++) {
        int s = slot[t * 2 + k];
        if (s >= 0) {
            float wk = w[t * 2 + k];
            ushort4 y = ((const ushort4*)(Ye + (size_t)s * D_))[tid];
            r.x += wk * b2f(y.x); r.y += wk * b2f(y.y);
            r.z += wk * b2f(y.z); r.w += wk * b2f(y.w);
        }
    }
    ((float4*)(out + (size_t)t * D_))[tid] = r;
}

extern "C" void kernel_launch(void* const* d_in, const int* in_sizes, int n_in,
                              void* d_out, int out_size, void* d_ws, size_t ws_size,
                              hipStream_t stream) {
    const float* x  = (const float*)d_in[0];
    const float* Wr = (const float*)d_in[1];
    const float* W1 = (const float*)d_in[2];
    const float* W3 = (const float*)d_in[3];
    const float* W2 = (const float*)d_in[4];
    float* out = (float*)d_out;

    char* ws = (char*)d_ws;
    size_t off = 0;
    auto alloc = [&](size_t bytes) { void* p = ws + off; off += (bytes + 255) & ~(size_t)255; return p; };
    unsigned short* WT13 = (unsigned short*)alloc((size_t)E_ * 2 * F_ * D_ * 2);
    unsigned short* WT2  = (unsigned short*)alloc((size_t)E_ * D_ * F_ * 2);
    unsigned short* xe   = (unsigned short*)alloc((size_t)E_ * CAP_ * D_ * 2);
    unsigned short* Ye   = (unsigned short*)alloc((size_t)E_ * CAP_ * D_ * 2);
    int*   top_i = (int*)alloc(SP_ * 4);
    float* top_w = (float*)alloc(SP_ * 4);
    int*   slot  = (int*)alloc(SP_ * 4);
    int*   list  = (int*)alloc((size_t)E_ * CAP_ * 4);
    int*   count = (int*)alloc(E_ * 4);
    size_t hg8_bytes = (size_t)E_ * CAP_ * F_ * 2;
    size_t hg4_bytes = (size_t)EG_ * CAP_ * F_ * 2;
    bool use8 = (off + hg8_bytes + 256) <= ws_size;
    unsigned short* Hg = (unsigned short*)alloc(use8 ? hg8_bytes : hg4_bytes);

    dim3 tt(16, 16);
    transpose_conv64<<<dim3(F_ / 64, D_ / 64, E_), tt, 0, stream>>>(W1, WT13, D_, F_, (size_t)D_ * F_, (size_t)2 * F_ * D_);
    transpose_conv64<<<dim3(F_ / 64, D_ / 64, E_), tt, 0, stream>>>(W3, WT13 + (size_t)F_ * D_, D_, F_, (size_t)D_ * F_, (size_t)2 * F_ * D_);
    transpose_conv64<<<dim3(D_ / 64, F_ / 64, E_), tt, 0, stream>>>(W2, WT2, F_, D_, (size_t)F_ * D_, (size_t)D_ * F_);

    router_kernel<<<T_ / 4, 256, 0, stream>>>(x, Wr, top_i, top_w);
    scan_kernel<<<1, SCAN_T, 0, stream>>>(top_i, slot, list, count);
    dispatch_kernel<<<dim3(CAP_, E_), 256, 0, stream>>>(x, list, count, xe);

    if (use8) {
        for (int g = 0; g < 2; g++) {
            size_t eo = (size_t)g * EG_;
            gemm1_320<<<dim3(8, 32, EG_), 512, 0, stream>>>(
                xe + eo * CAP_ * D_, WT13 + eo * 2 * F_ * D_, Hg + eo * CAP_ * F_);
        }
        gemm2_8p<<<dim3(8, 4, 8), 512, 0, stream>>>(Hg, WT2, Ye);
    } else {
        for (int g = 0; g < 2; g++) {
            size_t eo = (size_t)g * EG_;
            gemm1_320<<<dim3(8, 32, EG_), 512, 0, stream>>>(
                xe + eo * CAP_ * D_, WT13 + eo * 2 * F_ * D_, Hg);
            gemm2_4p<<<dim3(CAP_ / 320, D_ / 128, EG_), 512, 0, stream>>>(
                Hg, WT2 + eo * D_ * F_, Ye + eo * CAP_ * D_);
        }
    }
    combine_kernel<<<T_, 256, 0, stream>>>(Ye, slot, top_w, out);
}

// Round 12
// 713.823 us; speedup vs baseline: 1.0211x; 1.0211x over previous
//
#include <hip/hip_runtime.h>
#include <math.h>

#define E_    8
#define D_    1024
#define F_    4096
#define T_    8192
#define CAP_  2560
#define SP_   (T_ * 2)
#define EG_   4

typedef __attribute__((ext_vector_type(4))) float f32x4;
typedef __attribute__((ext_vector_type(8))) short bf16x8;

__device__ __forceinline__ float b2f(unsigned short u) {
    union { unsigned int i; float f; } v; v.i = ((unsigned int)u) << 16; return v.f;
}
__device__ __forceinline__ unsigned short f2b(float f) {
    unsigned int u = __float_as_uint(f);
    unsigned int r = (u + 0x7fff + ((u >> 16) & 1)) >> 16;
    return (unsigned short)r;
}
__device__ __forceinline__ void async16(void* lds, const void* g) {
    __builtin_amdgcn_global_load_lds(
        (const __attribute__((address_space(1))) unsigned int*)g,
        (__attribute__((address_space(3))) unsigned int*)lds, 16, 0, 0);
}

// Stage one 64-row x 64-col bf16 chunk (8KB): linear LDS dest, inverse-swizzled
// global source (rule #21).  goff hoisted by caller.
__device__ __forceinline__ void stage64o(unsigned short* ldsb, const unsigned short* g,
                                         size_t goff, int tid) {
    async16(ldsb + tid * 8, g + goff);
}
__device__ __forceinline__ void stage128o(unsigned short* ldsb, const unsigned short* g,
                                          size_t goff, int ldk, int tid) {
    stage64o(ldsb, g, goff, tid);
    stage64o(ldsb + 4096, g + (size_t)64 * ldk, goff, tid);
}

// ---------------- router: fp64 logits, top-2, softmax ----------------
__global__ void router_kernel(const float* __restrict__ x, const float* __restrict__ Wr,
                              int* __restrict__ top_i, float* __restrict__ top_w) {
    int wid = threadIdx.x >> 6, lane = threadIdx.x & 63;
    int t = blockIdx.x * 4 + wid;
    double s[E_];
    #pragma unroll
    for (int e = 0; e < E_; e++) s[e] = 0.0;
    const float* xr = x + (size_t)t * D_;
    for (int j = 0; j < D_ / 64; j++) {
        int d = lane + 64 * j;
        double xv = (double)xr[d];
        const float* wr = Wr + d * E_;
        #pragma unroll
        for (int e = 0; e < E_; e++) s[e] += xv * (double)wr[e];
    }
    #pragma unroll
    for (int off = 32; off >= 1; off >>= 1) {
        #pragma unroll
        for (int e = 0; e < E_; e++) s[e] += __shfl_xor(s[e], off, 64);
    }
    if (lane == 0) {
        double best = -1e300, sec = -1e300; int bi = 0, si = 0;
        #pragma unroll
        for (int e = 0; e < E_; e++) {
            double v = s[e];
            v = v > 1e4 ? 1e4 : (v < -1e4 ? -1e4 : v);
            if (v > best) { sec = best; si = bi; best = v; bi = e; }
            else if (v > sec) { sec = v; si = e; }
        }
        double e1 = exp(sec - best);
        double denom = 1.0 + e1 + 1e-12;
        top_i[t * 2 + 0] = bi;  top_i[t * 2 + 1] = si;
        top_w[t * 2 + 0] = (float)(1.0 / denom);
        top_w[t * 2 + 1] = (float)(e1 / denom);
    }
}

// -------- stable per-expert position scan + capacity prune (1 block) --------
#define SCAN_T 256
#define CHUNK  (SP_ / SCAN_T)
__global__ void scan_kernel(const int* __restrict__ top_i,
                            int* __restrict__ slot, int* __restrict__ list,
                            int* __restrict__ count) {
    __shared__ int lc[SCAN_T][E_];
    int tid = threadIdx.x;
    int cnt[E_];
    #pragma unroll
    for (int e = 0; e < E_; e++) cnt[e] = 0;
    int base = tid * CHUNK;
    for (int i = 0; i < CHUNK; i++) cnt[top_i[base + i]]++;
    #pragma unroll
    for (int e = 0; e < E_; e++) lc[tid][e] = cnt[e];
    __syncthreads();
    if (tid < E_) {
        int run = 0;
        for (int i = 0; i < SCAN_T; i++) { int c = lc[i][tid]; lc[i][tid] = run; run += c; }
        count[tid] = run;
    }
    __syncthreads();
    int off[E_];
    #pragma unroll
    for (int e = 0; e < E_; e++) off[e] = lc[tid][e];
    for (int i = 0; i < CHUNK; i++) {
        int s = base + i;
        int e = top_i[s];
        int p = off[e]++;
        if (p < CAP_) { slot[s] = e * CAP_ + p; list[e * CAP_ + p] = s; }
        else slot[s] = -1;
    }
}

// ---------------- dispatch: pack x rows into xe (bf16), zero pads ----------------
__global__ void dispatch_kernel(const float* __restrict__ x, const int* __restrict__ list,
                                const int* __restrict__ count, unsigned short* __restrict__ xe) {
    int c = blockIdx.x, e = blockIdx.y, tid = threadIdx.x;
    unsigned short* dst = xe + ((size_t)e * CAP_ + c) * D_;
    ushort4 o;
    if (c < count[e]) {
        int t = list[e * CAP_ + c] >> 1;
        float4 v = ((const float4*)(x + (size_t)t * D_))[tid];
        o.x = f2b(v.x); o.y = f2b(v.y); o.z = f2b(v.z); o.w = f2b(v.w);
    } else { o.x = 0; o.y = 0; o.z = 0; o.w = 0; }
    ((ushort4*)dst)[tid] = o;
}

// -------- fused transpose + fp32->bf16 for W1, W3, W2 in ONE launch --------
// grid (64,16,24): z = which*8 + e; which 0:W1->WT13[:F], 1:W3->WT13[F:], 2:W2->WT2.
// W1/W3: R=D,C=F, tile (c0=bx*64, r0=by*64).  W2: R=F,C=D, (c0=by*64, r0=bx*64).
__global__ void transpose_all(const float* __restrict__ W1, const float* __restrict__ W3,
                              const float* __restrict__ W2,
                              unsigned short* __restrict__ WT13, unsigned short* __restrict__ WT2) {
    __shared__ float tile[64][69];
    int slice = blockIdx.z;
    int e = slice & 7;
    int which = slice >> 3;
    const float* s; unsigned short* d; int R, C, c0, r0;
    if (which == 0) {
        s = W1 + (size_t)e * D_ * F_; d = WT13 + (size_t)e * 2 * F_ * D_;
        R = D_; C = F_; c0 = blockIdx.x * 64; r0 = blockIdx.y * 64;
    } else if (which == 1) {
        s = W3 + (size_t)e * D_ * F_; d = WT13 + (size_t)e * 2 * F_ * D_ + (size_t)F_ * D_;
        R = D_; C = F_; c0 = blockIdx.x * 64; r0 = blockIdx.y * 64;
    } else {
        s = W2 + (size_t)e * F_ * D_; d = WT2 + (size_t)e * D_ * F_;
        R = F_; C = D_; c0 = blockIdx.y * 64; r0 = blockIdx.x * 64;
    }
    int tx = threadIdx.x, ty = threadIdx.y;
    #pragma unroll
    for (int i = 0; i < 4; i++) {
        int row = ty + i * 16;
        float4 v = *(const float4*)(s + (size_t)(r0 + row) * C + c0 + 4 * tx);
        tile[row][4 * tx + 0] = v.x; tile[row][4 * tx + 1] = v.y;
        tile[row][4 * tx + 2] = v.z; tile[row][4 * tx + 3] = v.w;
    }
    __syncthreads();
    #pragma unroll
    for (int i = 0; i < 4; i++) {
        int c = ty + i * 16;
        ushort4 o;
        o.x = f2b(tile[4 * tx + 0][c]);
        o.y = f2b(tile[4 * tx + 1][c]);
        o.z = f2b(tile[4 * tx + 2][c]);
        o.w = f2b(tile[4 * tx + 3][c]);
        *(ushort4*)(d + (size_t)(c0 + c) * R + r0 + 4 * tx) = o;
    }
}

// ============================================================================
// gemm1_8p (persistent-m, round-8/10 proven best): H[e] = silu(xe@W1)*(xe@W3).
// Grid (2,32,EG) = 256 blocks = 1/CU; 5 m-chunks x full K per block;
// cross-boundary prefetch on tail iterations.  At m248's documented K=1024
// grouped-GEMM parity (~840 TF) — structural ceiling for this template.
// ============================================================================
#define G1_PHASE(ABUF, MP, LOADB, BBUF, STAGE, VMC)                            \
  {                                                                            \
    bf16x8 af[2][2];                                                           \
    _Pragma("unroll")                                                          \
    for (int mi = 0; mi < 2; mi++) {                                           \
      af[mi][0] = *(const bf16x8*)(aB0 + (ABUF) * 32768 + ((MP) * 2 + mi) * 2048); \
      af[mi][1] = *(const bf16x8*)(aB1 + (ABUF) * 32768 + ((MP) * 2 + mi) * 2048); \
    }                                                                          \
    if (LOADB) {                                                               \
      _Pragma("unroll")                                                        \
      for (int n = 0; n < 2; n++) {                                            \
        b1f[n][0] = *(const bf16x8*)(b1k0 + (BBUF) * 16384 + n * 2048);        \
        b1f[n][1] = *(const bf16x8*)(b1k1 + (BBUF) * 16384 + n * 2048);        \
        b3f[n][0] = *(const bf16x8*)(b3k0 + (BBUF) * 16384 + n * 2048);        \
        b3f[n][1] = *(const bf16x8*)(b3k1 + (BBUF) * 16384 + n * 2048);        \
      }                                                                        \
    }                                                                          \
    STAGE;                                                                     \
    __builtin_amdgcn_s_barrier();                                              \
    asm volatile("s_waitcnt lgkmcnt(0)" ::: "memory");                         \
    __builtin_amdgcn_sched_barrier(0);                                         \
    __builtin_amdgcn_s_setprio(1);                                             \
    _Pragma("unroll")                                                          \
    for (int mi = 0; mi < 2; mi++)                                             \
      _Pragma("unroll")                                                        \
      for (int n = 0; n < 2; n++)                                              \
        _Pragma("unroll")                                                      \
        for (int kk = 0; kk < 2; kk++) {                                       \
          acc1[(MP) * 2 + mi][n] = __builtin_amdgcn_mfma_f32_16x16x32_bf16(    \
              af[mi][kk], b1f[n][kk], acc1[(MP) * 2 + mi][n], 0, 0, 0);        \
          acc3[(MP) * 2 + mi][n] = __builtin_amdgcn_mfma_f32_16x16x32_bf16(    \
              af[mi][kk], b3f[n][kk], acc3[(MP) * 2 + mi][n], 0, 0, 0);        \
        }                                                                      \
    __builtin_amdgcn_s_setprio(0);                                             \
    if (VMC) asm volatile("s_waitcnt vmcnt(4)" ::: "memory");                  \
    __builtin_amdgcn_s_barrier();                                              \
  }

__global__ __launch_bounds__(512, 2) void gemm1_8p(
    const unsigned short* __restrict__ xe,
    const unsigned short* __restrict__ WT13,
    unsigned short* __restrict__ H) {
    __shared__ unsigned short As[2 * 2 * 8192];
    __shared__ unsigned short B1s[2 * 8192];
    __shared__ unsigned short B3s[2 * 8192];
    const int tid = threadIdx.x;
    const int lane = tid & 63, wid = tid >> 6;
    const int wr = wid >> 2, wc = wid & 3;
    const int lrow = lane & 15, lhi = lane >> 4;
    const int fid = blockIdx.x + 2 * (blockIdx.y + 32 * blockIdx.z);
    const int swz = (fid & 7) * 32 + (fid >> 3);
    const int bx = swz & 1;
    const int bn = (swz >> 1) & 31;
    const int e  = swz >> 6;
    const int n0 = bn * 128;
    const unsigned short* Abase = xe + (size_t)e * CAP_ * D_;
    const unsigned short* B1 = WT13 + (size_t)e * 2 * F_ * D_ + (size_t)n0 * D_;
    const unsigned short* B3 = B1 + (size_t)F_ * D_;
    unsigned short* Hout = H + (size_t)e * CAP_ * F_;

    const int xsw = lrow & 7;
    const char* aB0  = (const char*)As  + wr * 16384 + lrow * 128 + ((lhi    ) ^ xsw) * 16;
    const char* aB1  = (const char*)As  + wr * 16384 + lrow * 128 + ((4 + lhi) ^ xsw) * 16;
    const char* b1k0 = (const char*)B1s + wc * 4096  + lrow * 128 + ((lhi    ) ^ xsw) * 16;
    const char* b1k1 = (const char*)B1s + wc * 4096  + lrow * 128 + ((4 + lhi) ^ xsw) * 16;
    const char* b3k0 = (const char*)B3s + wc * 4096  + lrow * 128 + ((lhi    ) ^ xsw) * 16;
    const char* b3k1 = (const char*)B3s + wc * 4096  + lrow * 128 + ((4 + lhi) ^ xsw) * 16;
    const size_t goff = (size_t)(tid >> 3) * D_ + (size_t)(((tid & 7) ^ ((tid >> 3) & 7)) * 8);

    f32x4 acc1[8][2], acc3[8][2];
    #pragma unroll
    for (int m = 0; m < 8; m++)
        #pragma unroll
        for (int n = 0; n < 2; n++) {
            f32x4 z = {0.f, 0.f, 0.f, 0.f};
            acc1[m][n] = z; acc3[m][n] = z;
        }
    bf16x8 b1f[2][2], b3f[2][2];

    {
        const unsigned short* A0 = Abase + (size_t)(bx * 5) * 256 * D_;
        stage128o(As,            A0, goff, D_, tid);
        stage128o(As + 8192,     A0 + (size_t)128 * D_, goff, D_, tid);
        stage128o(B1s,           B1, goff, D_, tid);
        stage128o(B3s,           B3, goff, D_, tid);
        stage128o(B1s + 8192,    B1 + 64, goff, D_, tid);
        stage128o(B3s + 8192,    B3 + 64, goff, D_, tid);
    }
    asm volatile("s_waitcnt vmcnt(4)" ::: "memory");
    __builtin_amdgcn_s_barrier();

    for (int j = 0; j < 5; ++j) {
        const int mt = bx * 5 + j;
        const unsigned short* Acur  = Abase + (size_t)mt * 256 * D_;
        const unsigned short* Anext = Abase + (size_t)(mt + (j < 4 ? 1 : 0)) * 256 * D_;

        for (int it = 0; it < 8; ++it) {
            const int k1 = (2 * it + 1) * 64;
            const bool last = (it == 7);
            const unsigned short* A2 = last ? Anext : Acur + (2 * it + 2) * 64;
            const int kB2 = last ? 0  : (2 * it + 2) * 64;
            const int kB3 = last ? 64 : (2 * it + 3) * 64;
            G1_PHASE(0, 0, 1, 0, stage128o(As + 16384,        Acur + k1, goff, D_, tid), 0)
            G1_PHASE(0, 1, 0, 0, stage128o(As + 16384 + 8192, Acur + (size_t)128 * D_ + k1, goff, D_, tid), 0)
            G1_PHASE(0, 2, 0, 0, stage128o(B1s,               B1 + kB2, goff, D_, tid), 0)
            G1_PHASE(0, 3, 0, 0, stage128o(B3s,               B3 + kB2, goff, D_, tid), 1)
            G1_PHASE(1, 0, 1, 1, stage128o(As,                A2, goff, D_, tid), 0)
            G1_PHASE(1, 1, 0, 1, stage128o(As + 8192,         A2 + (size_t)128 * D_, goff, D_, tid), 0)
            G1_PHASE(1, 2, 0, 1, stage128o(B1s + 8192,        B1 + kB3, goff, D_, tid), 0)
            G1_PHASE(1, 3, 0, 1, stage128o(B3s + 8192,        B3 + kB3, goff, D_, tid), 1)
        }

        const int crow = mt * 256 + wr * 128 + lhi * 4;
        const int ccol = n0 + wc * 32 + lrow;
        #pragma unroll
        for (int m = 0; m < 8; m++)
            #pragma unroll
            for (int n = 0; n < 2; n++)
                #pragma unroll
                for (int r = 0; r < 4; r++) {
                    float g1 = acc1[m][n][r], g3 = acc3[m][n][r];
                    float h = g1 / (1.f + expf(-g1)) * g3;
                    Hout[(size_t)(crow + m * 16 + r) * F_ + ccol + n * 16] = f2b(h);
                }
        #pragma unroll
        for (int m = 0; m < 8; m++)
            #pragma unroll
            for (int n = 0; n < 2; n++) {
                f32x4 z = {0.f, 0.f, 0.f, 0.f};
                acc1[m][n] = z; acc3[m][n] = z;
            }
    }
}

// ============================================================================
// gemm2_8p (round-10 proven): Ye[e] = H[e] @ WT2[e]^T for ALL 8 experts.
// ============================================================================
#define G2N_PHASE(ABUF, MH, KK, LB0, LB1, BBUF, STAGE, VMC)                    \
  {                                                                            \
    bf16x8 af[5];                                                              \
    _Pragma("unroll")                                                          \
    for (int mi = 0; mi < 5; mi++)                                             \
      af[mi] = *(const bf16x8*)(g2a##KK + (ABUF) * 40960 + ((MH) * 5 + mi) * 2048); \
    if (LB0) {                                                                 \
      _Pragma("unroll")                                                        \
      for (int n = 0; n < 4; n++)                                              \
        bfr0[n] = *(const bf16x8*)(g2b0_ + (BBUF) * 32768 + n * 2048);         \
    }                                                                          \
    if (LB1) {                                                                 \
      _Pragma("unroll")                                                        \
      for (int n = 0; n < 4; n++)                                              \
        bfr1[n] = *(const bf16x8*)(g2b1_ + (BBUF) * 32768 + n * 2048);         \
    }                                                                          \
    STAGE;                                                                     \
    __builtin_amdgcn_s_barrier();                                              \
    asm volatile("s_waitcnt lgkmcnt(0)" ::: "memory");                         \
    __builtin_amdgcn_sched_barrier(0);                                         \
    __builtin_amdgcn_s_setprio(1);                                             \
    _Pragma("unroll")                                                          \
    for (int mi = 0; mi < 5; mi++)                                             \
      _Pragma("unroll")                                                        \
      for (int n = 0; n < 4; n++)                                              \
        acc[(MH) * 5 + mi][n] = __builtin_amdgcn_mfma_f32_16x16x32_bf16(       \
            af[mi], bfr##KK[n], acc[(MH) * 5 + mi][n], 0, 0, 0);               \
    __builtin_amdgcn_s_setprio(0);                                             \
    if (VMC) asm volatile("s_waitcnt vmcnt(4)" ::: "memory");                  \
    __builtin_amdgcn_s_barrier();                                              \
  }

__global__ __launch_bounds__(512, 2) void gemm2_8p(
    const unsigned short* __restrict__ Hb,   // [8][CAP][F]
    const unsigned short* __restrict__ WT2,  // [8][D][F]
    unsigned short* __restrict__ Ye) {       // [8][CAP][D]
    __shared__ unsigned short As[2 * 20480];      // 80KB (320x64 per buf)
    __shared__ unsigned short Bs[2 * 16384];      // 64KB (256x64 per buf)
    const int tid = threadIdx.x;
    const int lane = tid & 63, wid = tid >> 6;
    const int wr = wid >> 2, wc = wid & 3;
    const int lrow = lane & 15, lhi = lane >> 4;
    const int fid = blockIdx.x + 8 * (blockIdx.y + 4 * blockIdx.z);
    const int swz = (fid & 7) * 32 + (fid >> 3);
    const int bm = swz & 7;
    const int bn = (swz >> 3) & 3;
    const int e  = swz >> 5;
    const int m0 = bm * 320, n0 = bn * 256;
    const unsigned short* A = Hb + (size_t)e * CAP_ * F_ + (size_t)m0 * F_;
    const unsigned short* B = WT2 + (size_t)e * D_ * F_ + (size_t)n0 * F_;
    unsigned short* C = Ye + (size_t)e * CAP_ * D_;

    const int xsw = lrow & 7;
    const char* g2a0  = (const char*)As + wr * 20480 + lrow * 128 + ((lhi    ) ^ xsw) * 16;
    const char* g2a1  = (const char*)As + wr * 20480 + lrow * 128 + ((4 + lhi) ^ xsw) * 16;
    const char* g2b0_ = (const char*)Bs + wc * 8192  + lrow * 128 + ((lhi    ) ^ xsw) * 16;
    const char* g2b1_ = (const char*)Bs + wc * 8192  + lrow * 128 + ((4 + lhi) ^ xsw) * 16;
    const size_t goff = (size_t)(tid >> 3) * F_ + (size_t)(((tid & 7) ^ ((tid >> 3) & 7)) * 8);

    f32x4 acc[10][4];
    #pragma unroll
    for (int m = 0; m < 10; m++)
        #pragma unroll
        for (int n = 0; n < 4; n++) { f32x4 z = {0.f, 0.f, 0.f, 0.f}; acc[m][n] = z; }
    bf16x8 bfr0[4], bfr1[4];

    #define STA0(BUF, SRC)                                                      \
        { stage64o(As + (BUF) * 20480,        (SRC), goff, tid);                \
          stage64o(As + (BUF) * 20480 + 4096, (SRC) + (size_t)64  * F_, goff, tid); \
          stage64o(As + (BUF) * 20480 + 8192, (SRC) + (size_t)128 * F_, goff, tid); }
    #define STA1(BUF, SRC)                                                      \
        { stage64o(As + (BUF) * 20480 + 12288, (SRC) + (size_t)192 * F_, goff, tid); \
          stage64o(As + (BUF) * 20480 + 16384, (SRC) + (size_t)256 * F_, goff, tid); }
    #define STB0(BUF, SRC)                                                      \
        { stage64o(Bs + (BUF) * 16384,        (SRC), goff, tid);                \
          stage64o(Bs + (BUF) * 16384 + 4096, (SRC) + (size_t)64 * F_, goff, tid); }
    #define STB1(BUF, SRC)                                                      \
        { stage64o(Bs + (BUF) * 16384 + 8192,  (SRC) + (size_t)128 * F_, goff, tid); \
          stage64o(Bs + (BUF) * 16384 + 12288, (SRC) + (size_t)192 * F_, goff, tid); }

    STA0(0, A) STA1(0, A)
    STB0(0, B) STB1(0, B)
    STB0(1, B + 64) STB1(1, B + 64)
    asm volatile("s_waitcnt vmcnt(4)" ::: "memory");
    __builtin_amdgcn_s_barrier();

    for (int it = 0; it < 32; ++it) {                 // NT=64, 2 K-tiles/iter
        const int t = 2 * it;
        const int k1 = (t + 1) * 64;
        const int k2 = (t + 2 < 64 ? t + 2 : 63) * 64;
        const int k3 = (t + 3 < 64 ? t + 3 : 63) * 64;
        G2N_PHASE(0, 0, 0, 1, 0, 0, STA0(1, A + k1), 0)
        G2N_PHASE(0, 1, 0, 0, 1, 0, STA1(1, A + k1), 0)
        G2N_PHASE(0, 0, 1, 0, 0, 0, STB0(0, B + k2), 0)
        G2N_PHASE(0, 1, 1, 0, 0, 0, STB1(0, B + k2), 1)
        G2N_PHASE(1, 0, 0, 1, 0, 1, STA0(0, A + k2), 0)
        G2N_PHASE(1, 1, 0, 0, 1, 1, STA1(0, A + k2), 0)
        G2N_PHASE(1, 0, 1, 0, 0, 1, STB0(1, B + k3), 0)
        G2N_PHASE(1, 1, 1, 0, 0, 1, STB1(1, B + k3), 1)
    }
    #undef STA0
    #undef STA1
    #undef STB0
    #undef STB1

    const int crow = m0 + wr * 160 + lhi * 4;
    const int ccol = n0 + wc * 64 + lrow;
    #pragma unroll
    for (int m = 0; m < 10; m++)
        #pragma unroll
        for (int n = 0; n < 4; n++)
            #pragma unroll
            for (int r = 0; r < 4; r++)
                C[(size_t)(crow + m * 16 + r) * D_ + ccol + n * 16] = f2b(acc[m][n][r]);
}

// ============================================================================
// gemm2_4p (fallback when ws too small for 8-expert Hg)
// ============================================================================
#define G2_PHASE(ABUF, MH, LOADB, BBUF, STAGE, VMC)                            \
  {                                                                            \
    bf16x8 af[5][2];                                                           \
    _Pragma("unroll")                                                          \
    for (int mi = 0; mi < 5; mi++) {                                           \
      af[mi][0] = *(const bf16x8*)(f2a0 + (ABUF) * 40960 + ((MH) * 5 + mi) * 2048); \
      af[mi][1] = *(const bf16x8*)(f2a1 + (ABUF) * 40960 + ((MH) * 5 + mi) * 2048); \
    }                                                                          \
    if (LOADB) {                                                               \
      _Pragma("unroll")                                                        \
      for (int n = 0; n < 2; n++) {                                            \
        bf[n][0] = *(const bf16x8*)(f2b0 + (BBUF) * 16384 + n * 2048);         \
        bf[n][1] = *(const bf16x8*)(f2b1 + (BBUF) * 16384 + n * 2048);         \
      }                                                                        \
    }                                                                          \
    STAGE;                                                                     \
    __builtin_amdgcn_s_barrier();                                              \
    asm volatile("s_waitcnt lgkmcnt(0)" ::: "memory");                         \
    __builtin_amdgcn_sched_barrier(0);                                         \
    __builtin_amdgcn_s_setprio(1);                                             \
    _Pragma("unroll")                                                          \
    for (int mi = 0; mi < 5; mi++)                                             \
      _Pragma("unroll")                                                        \
      for (int n = 0; n < 2; n++)                                              \
        _Pragma("unroll")                                                      \
        for (int kk = 0; kk < 2; kk++)                                         \
          acc[(MH) * 5 + mi][n] = __builtin_amdgcn_mfma_f32_16x16x32_bf16(     \
              af[mi][kk], bf[n][kk], acc[(MH) * 5 + mi][n], 0, 0, 0);          \
    __builtin_amdgcn_s_setprio(0);                                             \
    if (VMC) asm volatile("s_waitcnt vmcnt(2)" ::: "memory");                  \
    __builtin_amdgcn_s_barrier();                                              \
  }

__global__ __launch_bounds__(512, 2) void gemm2_4p(
    const unsigned short* __restrict__ Hb,
    const unsigned short* __restrict__ WT2,
    unsigned short* __restrict__ Ye) {
    __shared__ unsigned short As[2 * 20480];
    __shared__ unsigned short Bs[2 * 8192];
    const int tid = threadIdx.x;
    const int lane = tid & 63, wid = tid >> 6;
    const int wr = wid >> 2, wc = wid & 3;
    const int lrow = lane & 15, lhi = lane >> 4;
    const int fid = blockIdx.x + 8 * (blockIdx.y + 8 * blockIdx.z);
    const int swz = (fid & 7) * 32 + (fid >> 3);
    const int bm = swz & 7;
    const int bn = (swz >> 3) & 7;
    const int e  = swz >> 6;
    const int m0 = bm * 320, n0 = bn * 128;
    const unsigned short* A = Hb + (size_t)e * CAP_ * F_ + (size_t)m0 * F_;
    const unsigned short* B = WT2 + (size_t)e * D_ * F_ + (size_t)n0 * F_;
    unsigned short* C = Ye + (size_t)e * CAP_ * D_;

    const int xsw = lrow & 7;
    const char* f2a0 = (const char*)As + wr * 20480 + lrow * 128 + ((lhi    ) ^ xsw) * 16;
    const char* f2a1 = (const char*)As + wr * 20480 + lrow * 128 + ((4 + lhi) ^ xsw) * 16;
    const char* f2b0 = (const char*)Bs + wc * 4096  + lrow * 128 + ((lhi    ) ^ xsw) * 16;
    const char* f2b1 = (const char*)Bs + wc * 4096  + lrow * 128 + ((4 + lhi) ^ xsw) * 16;
    const size_t goff = (size_t)(tid >> 3) * F_ + (size_t)(((tid & 7) ^ ((tid >> 3) & 7)) * 8);

    f32x4 acc[10][2];
    #pragma unroll
    for (int m = 0; m < 10; m++)
        #pragma unroll
        for (int n = 0; n < 2; n++) { f32x4 z = {0.f, 0.f, 0.f, 0.f}; acc[m][n] = z; }
    bf16x8 bf[2][2];

    #define STAGE_A(BUF, KOFF)                                                  \
        { _Pragma("unroll")                                                     \
          for (int j = 0; j < 5; j++)                                           \
            stage64o(As + (BUF) * 20480 + j * 4096,                             \
                     A + (size_t)(j * 64) * F_ + (KOFF), goff, tid); }
    #define STAGE_B(BUF, KOFF)                                                  \
        { stage64o(Bs + (BUF) * 8192,        B + (KOFF), goff, tid);            \
          stage64o(Bs + (BUF) * 8192 + 4096, B + (size_t)64 * F_ + (KOFF), goff, tid); }

    STAGE_A(0, 0)
    STAGE_B(0, 0)
    STAGE_B(1, 64)
    asm volatile("s_waitcnt vmcnt(2)" ::: "memory");
    __builtin_amdgcn_s_barrier();

    for (int it = 0; it < 32; ++it) {
        const int t = 2 * it;
        const int k1 = (t + 1) * 64;
        const int k2 = (t + 2 < 64 ? t + 2 : 63) * 64;
        const int k3 = (t + 3 < 64 ? t + 3 : 63) * 64;
        G2_PHASE(0, 0, 1, 0, STAGE_A(1, k1), 0)
        G2_PHASE(0, 1, 0, 0, STAGE_B(0, k2), 1)
        G2_PHASE(1, 0, 1, 1, STAGE_A(0, k2), 0)
        G2_PHASE(1, 1, 0, 1, STAGE_B(1, k3), 1)
    }
    #undef STAGE_A
    #undef STAGE_B

    const int crow = m0 + wr * 160 + lhi * 4;
    const int ccol = n0 + wc * 32 + lrow;
    #pragma unroll
    for (int m = 0; m < 10; m++)
        #pragma unroll
        for (int n = 0; n < 2; n++)
            #pragma unroll
            for (int r = 0; r < 4; r++)
                C[(size_t)(crow + m * 16 + r) * D_ + ccol + n * 16] = f2b(acc[m][n][r]);
}

// ---------------- combine: out[t] = sum_k w[t,k] * Ye[slot(t,k)] ----------------
__global__ void combine_kernel(const unsigned short* __restrict__ Ye, const int* __restrict__ slot,
                               const float* __restrict__ w, float* __restrict__ out) {
    int t = blockIdx.x, tid = threadIdx.x;
    float4 r = {0.f, 0.f, 0.f, 0.f};
    #pragma unroll
    for (int k = 0; k < 2; k++) {
        int s = slot[t * 2 + k];
        if (s >= 0) {
            float wk = w[t * 2 + k];
            ushort4 y = ((const ushort4*)(Ye + (size_t)s * D_))[tid];
            r.x += wk * b2f(y.x); r.y += wk * b2f(y.y);
            r.z += wk * b2f(y.z); r.w += wk * b2f(y.w);
        }
    }
    ((float4*)(out + (size_t)t * D_))[tid] = r;
}

extern "C" void kernel_launch(void* const* d_in, const int* in_sizes, int n_in,
                              void* d_out, int out_size, void* d_ws, size_t ws_size,
                              hipStream_t stream) {
    const float* x  = (const float*)d_in[0];
    const float* Wr = (const float*)d_in[1];
    const float* W1 = (const float*)d_in[2];
    const float* W3 = (const float*)d_in[3];
    const float* W2 = (const float*)d_in[4];
    float* out = (float*)d_out;

    char* ws = (char*)d_ws;
    size_t off = 0;
    auto alloc = [&](size_t bytes) { void* p = ws + off; off += (bytes + 255) & ~(size_t)255; return p; };
    unsigned short* WT13 = (unsigned short*)alloc((size_t)E_ * 2 * F_ * D_ * 2);
    unsigned short* WT2  = (unsigned short*)alloc((size_t)E_ * D_ * F_ * 2);
    unsigned short* xe   = (unsigned short*)alloc((size_t)E_ * CAP_ * D_ * 2);
    unsigned short* Ye   = (unsigned short*)alloc((size_t)E_ * CAP_ * D_ * 2);
    int*   top_i = (int*)alloc(SP_ * 4);
    float* top_w = (float*)alloc(SP_ * 4);
    int*   slot  = (int*)alloc(SP_ * 4);
    int*   list  = (int*)alloc((size_t)E_ * CAP_ * 4);
    int*   count = (int*)alloc(E_ * 4);
    size_t hg8_bytes = (size_t)E_ * CAP_ * F_ * 2;
    size_t hg4_bytes = (size_t)EG_ * CAP_ * F_ * 2;
    bool use8 = (off + hg8_bytes + 256) <= ws_size;
    unsigned short* Hg = (unsigned short*)alloc(use8 ? hg8_bytes : hg4_bytes);

    // fused W1/W3/W2 transpose+convert: one launch, 24 slices
    transpose_all<<<dim3(64, 16, 24), dim3(16, 16), 0, stream>>>(W1, W3, W2, WT13, WT2);

    router_kernel<<<T_ / 4, 256, 0, stream>>>(x, Wr, top_i, top_w);
    scan_kernel<<<1, SCAN_T, 0, stream>>>(top_i, slot, list, count);
    dispatch_kernel<<<dim3(CAP_, E_), 256, 0, stream>>>(x, list, count, xe);

    if (use8) {
        for (int g = 0; g < 2; g++) {
            size_t eo = (size_t)g * EG_;
            gemm1_8p<<<dim3(2, 32, EG_), 512, 0, stream>>>(
                xe + eo * CAP_ * D_, WT13 + eo * 2 * F_ * D_, Hg + eo * CAP_ * F_);
        }
        gemm2_8p<<<dim3(8, 4, 8), 512, 0, stream>>>(Hg, WT2, Ye);
    } else {
        for (int g = 0; g < 2; g++) {
            size_t eo = (size_t)g * EG_;
            gemm1_8p<<<dim3(2, 32, EG_), 512, 0, stream>>>(
                xe + eo * CAP_ * D_, WT13 + eo * 2 * F_ * D_, Hg);
            gemm2_4p<<<dim3(CAP_ / 320, D_ / 128, EG_), 512, 0, stream>>>(
                Hg, WT2 + eo * D_ * F_, Ye + eo * CAP_ * D_);
        }
    }
    combine_kernel<<<T_, 256, 0, stream>>>(Ye, slot, top_w, out);
}